// Round 5
// baseline (356.173 us; speedup 1.0000x reference)
//
#include <hip/hip_runtime.h>
#include <hip/hip_bf16.h>
#include <math.h>

#define NIN 128
#define HC 128
#define NOUT 768

typedef __attribute__((ext_vector_type(8))) short bf16x8;
typedef __attribute__((ext_vector_type(4))) float f32x4;
typedef __attribute__((ext_vector_type(4))) unsigned short ushort4v;
typedef __attribute__((ext_vector_type(8))) unsigned short ushort8v;

__device__ __forceinline__ unsigned short f2bf(float f) {
    __hip_bfloat16 h = __float2bfloat16(f);
    return *(unsigned short*)&h;
}

// ---------------- prep: W[k][n] fp32 -> Wt[n][k] bf16 (4 weights) ----------------
__global__ __launch_bounds__(256) void prep_w(
    const float* __restrict__ Wq, const float* __restrict__ Wk,
    const float* __restrict__ Wv, const float* __restrict__ Wsk,
    unsigned short* __restrict__ Wtb)
{
    const float* W = (blockIdx.x == 0) ? Wq : (blockIdx.x == 1) ? Wk
                   : (blockIdx.x == 2) ? Wv : Wsk;
    unsigned short* out = Wtb + (size_t)blockIdx.x * 128 * 128;
    const int t = threadIdx.x;
    for (int s = 0; s < 16; ++s) {
        const int f = t + s * 256;           // float4 index (4096 total)
        const int k = f >> 5;
        const int n = (f & 31) * 4;
        float4 w4 = *(const float4*)(W + (size_t)k * 128 + n);
        out[(size_t)(n    ) * 128 + k] = f2bf(w4.x);
        out[(size_t)(n + 1) * 128 + k] = f2bf(w4.y);
        out[(size_t)(n + 2) * 128 + k] = f2bf(w4.z);
        out[(size_t)(n + 3) * 128 + k] = f2bf(w4.w);
    }
}

// ---------------- Kernel A: MFMA projections, all 4 weights per block ----------------
// LDS only for the x tile (34 KB -> 4 blocks/CU). B fragments read directly from
// global (128 KB shared by all blocks -> L1/L2 resident). One barrier total.
__global__ __launch_bounds__(256, 4) void gemm4_mfma(
    const float* __restrict__ x, const unsigned short* __restrict__ Wtb,
    const float* __restrict__ bq, const float* __restrict__ bk,
    const float* __restrict__ bv, const float* __restrict__ bsk,
    __hip_bfloat16* __restrict__ outbase, int N)
{
    __shared__ unsigned short At[128][136];   // row stride 272 B -> 2-way alias max
    const int tid = threadIdx.x;
    const int lane = tid & 63;
    const int wave = tid >> 6;
    const int rowBase = blockIdx.x * 128;
    const bool full = (rowBase + 128 <= N);

    // stage A: x fp32 -> bf16 LDS (coalesced float4 reads)
    #pragma unroll
    for (int s = 0; s < 16; ++s) {
        const int f = tid + s * 256;          // float4 idx
        const int r = f >> 5;
        const int cl = (f & 31) * 4;
        const int gr = rowBase + r;
        float4 a4 = make_float4(0.f, 0.f, 0.f, 0.f);
        if (full || gr < N) a4 = *(const float4*)(x + (size_t)gr * 128 + cl);
        ushort4v u;
        u.x = f2bf(a4.x); u.y = f2bf(a4.y); u.z = f2bf(a4.z); u.w = f2bf(a4.w);
        *(ushort4v*)&At[r][cl] = u;
    }
    __syncthreads();

    // A fragments to registers (A row = lane&15, k = (lane>>4)*8 + kk*32 + j)
    bf16x8 afr[2][4];
    #pragma unroll
    for (int m = 0; m < 2; ++m)
        #pragma unroll
        for (int kk = 0; kk < 4; ++kk)
            afr[m][kk] = *(bf16x8*)&At[wave * 32 + m * 16 + (lane & 15)]
                                    [kk * 32 + (lane >> 4) * 8];

    const int colb = lane & 15;
    const int kofs = (lane >> 4) * 8;

    for (int w = 0; w < 4; ++w) {
        const unsigned short* Wp = Wtb + (size_t)w * 128 * 128;
        const float* bias = (w == 0) ? bq : (w == 1) ? bk : (w == 2) ? bv : bsk;
        __hip_bfloat16* out = outbase + (size_t)w * (size_t)N * 128;

        f32x4 acc[2][8];
        #pragma unroll
        for (int m = 0; m < 2; ++m)
            #pragma unroll
            for (int nr = 0; nr < 8; ++nr)
                acc[m][nr] = (f32x4){0.f, 0.f, 0.f, 0.f};

        #pragma unroll
        for (int nr = 0; nr < 8; ++nr) {
            bf16x8 bfr[4];
            #pragma unroll
            for (int kk = 0; kk < 4; ++kk)
                bfr[kk] = *(const bf16x8*)(Wp + (size_t)(nr * 16 + colb) * 128
                                               + kk * 32 + kofs);
            #pragma unroll
            for (int kk = 0; kk < 4; ++kk) {
                #pragma unroll
                for (int m = 0; m < 2; ++m)
                    acc[m][nr] = __builtin_amdgcn_mfma_f32_16x16x32_bf16(
                        afr[m][kk], bfr[kk], acc[m][nr], 0, 0, 0);
            }
        }

        // store: C/D layout col = lane&15, row = (lane>>4)*4 + j
        #pragma unroll
        for (int nr = 0; nr < 8; ++nr) {
            const int col = nr * 16 + colb;
            const float bb = bias[col];
            #pragma unroll
            for (int m = 0; m < 2; ++m) {
                #pragma unroll
                for (int j = 0; j < 4; ++j) {
                    const int r = rowBase + wave * 32 + m * 16 + (lane >> 4) * 4 + j;
                    if (full || r < N)
                        out[(size_t)r * 128 + col] = __float2bfloat16(acc[m][nr][j] + bb);
                }
            }
        }
    }
}

// ---------------- CSR build ----------------
__global__ __launch_bounds__(256) void hist_kernel(
    const int* __restrict__ ei, int* __restrict__ cnt, int E)
{
    const int e = blockIdx.x * 256 + threadIdx.x;
    if (e < E) atomicAdd(cnt + ei[E + e], 1);
}

__global__ __launch_bounds__(1024) void scan_part(
    const int* __restrict__ cnt, int* __restrict__ start,
    int* __restrict__ bsum, int N)
{
    __shared__ int wsum[16];
    const int tid = threadIdx.x;
    const int lane = tid & 63;
    const int w = tid >> 6;
    const int i = blockIdx.x * 1024 + tid;
    const int v = (i < N) ? cnt[i] : 0;
    int xv = v;
    #pragma unroll
    for (int off = 1; off < 64; off <<= 1) {
        const int y = __shfl_up(xv, off, 64);
        if (lane >= off) xv += y;
    }
    if (lane == 63) wsum[w] = xv;
    __syncthreads();
    if (tid < 16) {
        int y = wsum[tid];
        #pragma unroll
        for (int off = 1; off < 16; off <<= 1) {
            const int z = __shfl_up(y, off, 64);
            if (tid >= off) y += z;
        }
        wsum[tid] = y;
    }
    __syncthreads();
    const int excl = (w > 0 ? wsum[w - 1] : 0) + xv - v;
    if (i < N) start[i] = excl;
    if (tid == 1023) bsum[blockIdx.x] = wsum[15];
}

__global__ __launch_bounds__(128) void scan_bsum(int* __restrict__ bsum, int NB)
{
    const int tid = threadIdx.x;
    __shared__ int w0tot;
    const int v = (tid < NB) ? bsum[tid] : 0;
    int xv = v;
    const int lane = tid & 63;
    #pragma unroll
    for (int off = 1; off < 64; off <<= 1) {
        const int y = __shfl_up(xv, off, 64);
        if (lane >= off) xv += y;
    }
    if (tid == 63) w0tot = xv;
    __syncthreads();
    const int incl = xv + ((tid >= 64) ? w0tot : 0);
    if (tid < NB) bsum[tid] = incl - v;     // exclusive
}

__global__ __launch_bounds__(256) void scan_add(
    int* __restrict__ start, int* __restrict__ cursor,
    const int* __restrict__ bsum, int N)
{
    const int i = blockIdx.x * 256 + threadIdx.x;
    if (i < N) {
        const int s = start[i] + bsum[i >> 10];
        start[i] = s;
        cursor[i] = s;
    }
}

__global__ __launch_bounds__(256) void scatter_kernel(
    const int* __restrict__ ei, int* __restrict__ cursor,
    int* __restrict__ csr_src, int E)
{
    const int e = blockIdx.x * 256 + threadIdx.x;
    if (e < E) {
        const int d = ei[E + e];
        const int pos = atomicAdd(cursor + d, 1);
        csr_src[pos] = ei[e];
    }
}

// ---------------- Kernel B: node-centric attention + gate (no atomics) ----------------
__global__ __launch_bounds__(256) void node_aggr(
    const __hip_bfloat16* __restrict__ q, const __hip_bfloat16* __restrict__ k,
    const __hip_bfloat16* __restrict__ v, const __hip_bfloat16* __restrict__ skip,
    const int* __restrict__ start, const int* __restrict__ cnt,
    const int* __restrict__ csr_src, const float* __restrict__ Wbeta,
    __hip_bfloat16* __restrict__ gout, int N)
{
    const int n = blockIdx.x * 4 + (threadIdx.x >> 6);
    if (n >= N) return;
    const int lane = threadIdx.x & 63;
    const int c = 2 * lane;
    const float scale = 0.17677669529663687f;   // 1/sqrt(32)

    const __hip_bfloat162 q2 = *(const __hip_bfloat162*)(q + (size_t)n * HC + c);
    const float qx = __bfloat162float(q2.x), qy = __bfloat162float(q2.y);

    const int s0 = start[n];
    const int e1 = s0 + cnt[n];
    float den = 0.f, a0 = 0.f, a1 = 0.f;
    int i = s0;
    for (; i + 1 < e1; i += 2) {
        const int sa = csr_src[i];
        const int sb = csr_src[i + 1];
        const __hip_bfloat162 k2a = *(const __hip_bfloat162*)(k + (size_t)sa * HC + c);
        const __hip_bfloat162 v2a = *(const __hip_bfloat162*)(v + (size_t)sa * HC + c);
        const __hip_bfloat162 k2b = *(const __hip_bfloat162*)(k + (size_t)sb * HC + c);
        const __hip_bfloat162 v2b = *(const __hip_bfloat162*)(v + (size_t)sb * HC + c);
        float pa = qx * __bfloat162float(k2a.x) + qy * __bfloat162float(k2a.y);
        float pb = qx * __bfloat162float(k2b.x) + qy * __bfloat162float(k2b.y);
        #pragma unroll
        for (int m = 1; m < 16; m <<= 1) {
            pa += __shfl_xor(pa, m, 64);
            pb += __shfl_xor(pb, m, 64);
        }
        const float exa = __expf(pa * scale);
        const float exb = __expf(pb * scale);
        den += exa + exb;
        a0 = fmaf(__bfloat162float(v2a.x), exa, fmaf(__bfloat162float(v2b.x), exb, a0));
        a1 = fmaf(__bfloat162float(v2a.y), exa, fmaf(__bfloat162float(v2b.y), exb, a1));
    }
    if (i < e1) {
        const int sa = csr_src[i];
        const __hip_bfloat162 k2a = *(const __hip_bfloat162*)(k + (size_t)sa * HC + c);
        const __hip_bfloat162 v2a = *(const __hip_bfloat162*)(v + (size_t)sa * HC + c);
        float pa = qx * __bfloat162float(k2a.x) + qy * __bfloat162float(k2a.y);
        #pragma unroll
        for (int m = 1; m < 16; m <<= 1) pa += __shfl_xor(pa, m, 64);
        const float exa = __expf(pa * scale);
        den += exa;
        a0 = fmaf(__bfloat162float(v2a.x), exa, a0);
        a1 = fmaf(__bfloat162float(v2a.y), exa, a1);
    }

    const float inv = 1.f / (den + 1e-16f);
    const float o0 = a0 * inv, o1 = a1 * inv;

    const __hip_bfloat162 s2 = *(const __hip_bfloat162*)(skip + (size_t)n * HC + c);
    const float sk0 = __bfloat162float(s2.x);
    const float sk1 = __bfloat162float(s2.y);

    float part = o0 * Wbeta[c]     + sk0 * Wbeta[HC + c]     + (o0 - sk0) * Wbeta[2 * HC + c]
               + o1 * Wbeta[c + 1] + sk1 * Wbeta[HC + c + 1] + (o1 - sk1) * Wbeta[2 * HC + c + 1];
    #pragma unroll
    for (int m = 1; m < 64; m <<= 1) part += __shfl_xor(part, m, 64);

    const float beta = 1.f / (1.f + __expf(-part));
    float r0 = beta * sk0 + (1.f - beta) * o0;
    float r1 = beta * sk1 + (1.f - beta) * o1;
    r0 = (r0 >= 0.f) ? r0 : 0.01f * r0;
    r1 = (r1 >= 0.f) ? r1 : 0.01f * r1;

    __hip_bfloat162 g2;
    g2.x = __float2bfloat16(r0);
    g2.y = __float2bfloat16(r1);
    *(__hip_bfloat162*)(gout + (size_t)n * HC + c) = g2;
}

// ---------------- pool per graph (batch sorted; binary search the range) ----------------
__global__ __launch_bounds__(128) void pool_graph(
    const __hip_bfloat16* __restrict__ gout, const int* __restrict__ batch,
    float* __restrict__ pooled, int N)
{
    const int g = blockIdx.x;
    const int t = threadIdx.x;
    int lo = 0, hi = N;
    while (lo < hi) { const int m = (lo + hi) >> 1; if (batch[m] < g) lo = m + 1; else hi = m; }
    int lo2 = lo, hi2 = N;
    while (lo2 < hi2) { const int m = (lo2 + hi2) >> 1; if (batch[m] < g + 1) lo2 = m + 1; else hi2 = m; }
    float acc = 0.f;
    for (int r = lo; r < lo2; ++r)
        acc += __bfloat162float(gout[(size_t)r * HC + t]);
    pooled[(size_t)g * HC + t] = acc / fmaxf((float)(lo2 - lo), 1.f);
}

// ---------------- final GEMM ----------------
__global__ __launch_bounds__(256) void final_gemm(
    const float* __restrict__ pooled,
    const float* __restrict__ W2, const float* __restrict__ b2,
    float* __restrict__ out, int G)
{
    const int g = blockIdx.x;
    __shared__ float p[HC];
    const int t = threadIdx.x;
    if (t < HC) p[t] = pooled[(size_t)g * HC + t];
    __syncthreads();
    for (int j = t; j < NOUT; j += 256) {
        float acc = b2[j];
        #pragma unroll 8
        for (int c = 0; c < HC; ++c) acc = fmaf(p[c], W2[(size_t)c * NOUT + j], acc);
        out[(size_t)g * NOUT + j] = acc;
    }
}

// ---------------- launch ----------------
extern "C" void kernel_launch(void* const* d_in, const int* in_sizes, int n_in,
                              void* d_out, int out_size, void* d_ws, size_t ws_size,
                              hipStream_t stream) {
    const float* x     = (const float*)d_in[0];
    const int*   ei    = (const int*)d_in[1];
    const int*   batch = (const int*)d_in[2];
    const float* Wq  = (const float*)d_in[3];  const float* bq  = (const float*)d_in[4];
    const float* Wk  = (const float*)d_in[5];  const float* bk  = (const float*)d_in[6];
    const float* Wv  = (const float*)d_in[7];  const float* bv  = (const float*)d_in[8];
    const float* Wsk = (const float*)d_in[9];  const float* bsk = (const float*)d_in[10];
    const float* Wbeta = (const float*)d_in[11];
    const float* W2  = (const float*)d_in[12]; const float* b2  = (const float*)d_in[13];

    const int N = in_sizes[0] / NIN;
    const int E = in_sizes[1] / 2;
    const int G = out_size / NOUT;

    char* ws = (char*)d_ws;
    const size_t nbQ = (size_t)N * HC * sizeof(__hip_bfloat16);
    __hip_bfloat16* q    = (__hip_bfloat16*)(ws);
    __hip_bfloat16* kk_  = (__hip_bfloat16*)(ws + nbQ);
    __hip_bfloat16* vv   = (__hip_bfloat16*)(ws + 2 * nbQ);
    __hip_bfloat16* skip = (__hip_bfloat16*)(ws + 3 * nbQ);
    char* p0 = ws + 4 * nbQ;
    unsigned short* Wtb = (unsigned short*)p0;            p0 += 4 * 128 * 128 * sizeof(unsigned short);
    int* cnt    = (int*)p0;                               p0 += (size_t)N * sizeof(int);
    int* start  = (int*)p0;                               p0 += (size_t)N * sizeof(int);
    int* cursor = (int*)p0;                               p0 += (size_t)N * sizeof(int);
    int* bsum   = (int*)p0;                               p0 += 1024 * sizeof(int);
    int* csr    = (int*)p0;                               p0 += (size_t)E * sizeof(int);
    __hip_bfloat16* gout = (__hip_bfloat16*)p0;           p0 += nbQ;
    float* pooled = (float*)p0;

    hipMemsetAsync(cnt, 0, (size_t)N * sizeof(int), stream);

    const int eb = (E + 255) / 256;
    const int NB = (N + 1023) / 1024;
    hist_kernel<<<eb, 256, 0, stream>>>(ei, cnt, E);
    scan_part<<<NB, 1024, 0, stream>>>(cnt, start, bsum, N);
    scan_bsum<<<1, 128, 0, stream>>>(bsum, NB);
    scan_add<<<(N + 255) / 256, 256, 0, stream>>>(start, cursor, bsum, N);
    scatter_kernel<<<eb, 256, 0, stream>>>(ei, cursor, csr, E);

    prep_w<<<4, 256, 0, stream>>>(Wq, Wk, Wv, Wsk, Wtb);
    gemm4_mfma<<<(N + 127) / 128, 256, 0, stream>>>(x, Wtb, bq, bk, bv, bsk, q, N);

    node_aggr<<<(N + 3) / 4, 256, 0, stream>>>(q, kk_, vv, skip, start, cnt, csr,
                                               Wbeta, gout, N);

    pool_graph<<<G, 128, 0, stream>>>(gout, batch, pooled, N);
    final_gemm<<<G, 256, 0, stream>>>(pooled, W2, b2, (float*)d_out, G);
}